// Round 10
// baseline (543.202 us; speedup 1.0000x reference)
//
#include <hip/hip_runtime.h>

// Chamfer distance, N=M=16384, D=3, f32 — EXACT pruned search.
// R9: brute force is issue-bound at ~43us (R2, 107% VALUBusy; floor 3
// instr/pair = 28us). Cut the pair count instead: counting-sort both sets
// into 2048 x-buckets; each query expands buckets outward from its own,
// terminating when the next bucket's min |dx|^2 >= best d^2 (bucket-EDGE
// bound -> exact regardless of within-bucket order). N(0,1)^3 data => NN
// dist ~0.05-0.4 => ~1-2% of candidates touched (~33M evals vs 536M).
// Two lanes per query (left/right scanner, best shared via shfl_xor(32))
// halve serial depth; sorted query order keeps waves coherent.

#define NPTS 16384
#define NB   2048
#define ORG  (-8.0f)
#define W    0.0078125f      // 1/128
#define IW   128.0f

__device__ __forceinline__ int bucket_of(float v) {
    int b = (int)((v - ORG) * IW);
    return min(max(b, 0), NB - 1);
}

// Histogram of x-coordinates per set. hist must be zeroed before (memset).
__global__ __launch_bounds__(256) void cd_hist(
        const float* __restrict__ x, const float* __restrict__ y,
        int* __restrict__ hist, int n, int m) {
    int i = blockIdx.x * 256 + threadIdx.x;
    if (i >= n + m) return;
    int set = (i < n) ? 0 : 1;
    int k = (i < n) ? i : i - n;
    const float* src = set ? y : x;
    atomicAdd(&hist[set * NB + bucket_of(src[3 * k])], 1);
}

// Exclusive scan of one set's histogram (blockIdx.x = set). Writes
// starts[set][0..NB] and cursor[set][0..NB-1] (= starts copy for scatter).
__global__ __launch_bounds__(1024) void cd_scan(
        const int* __restrict__ hist, int* __restrict__ starts,
        int* __restrict__ cursor) {
    __shared__ int sb[2][NB];
    const int* h = hist + blockIdx.x * NB;
    int t = threadIdx.x;
    sb[0][t] = h[t];
    sb[0][t + 1024] = h[t + 1024];
    __syncthreads();
    int src = 0;
    for (int d = 1; d < NB; d <<= 1) {
        int dst = src ^ 1;
#pragma unroll
        for (int k = 0; k < 2; ++k) {
            int i = t + k * 1024;
            int v = sb[src][i];
            if (i >= d) v += sb[src][i - d];
            sb[dst][i] = v;
        }
        __syncthreads();
        src = dst;
    }
    int* st = starts + blockIdx.x * (NB + 1);
    int* cu = cursor + blockIdx.x * NB;
#pragma unroll
    for (int k = 0; k < 2; ++k) {
        int i = t + k * 1024;
        int e = (i == 0) ? 0 : sb[src][i - 1];
        st[i] = e;
        cu[i] = e;
    }
    if (t == 0) st[NB] = sb[src][NB - 1];
}

// Scatter points into bucket-sorted float4 arrays (order within a bucket is
// arbitrary — exactness only relies on the bucket SET, and min is
// order-independent).
__global__ __launch_bounds__(256) void cd_scatter(
        const float* __restrict__ x, const float* __restrict__ y,
        int* __restrict__ cursor, float4* __restrict__ sx,
        float4* __restrict__ sy, int n, int m) {
    int i = blockIdx.x * 256 + threadIdx.x;
    if (i >= n + m) return;
    int set = (i < n) ? 0 : 1;
    int k = (i < n) ? i : i - n;
    const float* src = set ? y : x;
    float a = src[3 * k], b = src[3 * k + 1], c = src[3 * k + 2];
    int slot = atomicAdd(&cursor[set * NB + bucket_of(a)], 1);
    float4* dst = set ? sy : sx;
    dst[slot] = make_float4(a, b, c, 0.0f);
}

// One query = 2 lanes (l and l^32): half 0 scans bucket b0 then expands
// left; half 1 expands right. Shared best via shfl_xor(32) each round.
// Termination: my next bucket's min possible |dx|^2 >= best (bucket-edge
// bound, exact). Block = 128 thr = 2 waves = 64 queries; 512 blocks.
__global__ __launch_bounds__(128) void cd_search(
        const float4* __restrict__ sx, const float4* __restrict__ sy,
        const int* __restrict__ stx, const int* __restrict__ sty,
        float* __restrict__ minout, int n, int m) {
    const int lane = threadIdx.x & 63;
    const int wave = threadIdx.x >> 6;
    const int half = lane >> 5;
    const int qid = blockIdx.x * 64 + wave * 32 + (lane & 31);
    if (qid >= n + m) return;
    const int dir = (qid < n) ? 0 : 1;
    const int idx = dir ? (qid - n) : qid;

    const float4* Q = dir ? sy : sx;
    const float4* C = dir ? sx : sy;   // candidates = other set
    const int* cs = dir ? stx : sty;

    const float4 q = Q[idx];
    const int b0 = bucket_of(q.x);
    int b = half ? (b0 + 1) : b0;
    float best = INFINITY;

    for (;;) {
        float dm;
        bool valid;
        if (half) { valid = (b < NB);  dm = (ORG + b * W) - q.x; }
        else      { valid = (b >= 0);  dm = q.x - (ORG + (b + 1) * W); }
        dm = fmaxf(dm, 0.0f);
        bool go = valid && (dm * dm < best);
        int pgo = __shfl_xor((int)go, 32, 64);
        if (!go && !pgo) break;
        if (go) {
            int s = cs[b], e = cs[b + 1];
            int j = s;
            for (; j + 2 <= e; j += 2) {
                float4 c0 = C[j], c1 = C[j + 1];
                float dx0 = q.x - c0.x, dy0 = q.y - c0.y, dz0 = q.z - c0.z;
                float dx1 = q.x - c1.x, dy1 = q.y - c1.y, dz1 = q.z - c1.z;
                float d0 = fmaf(dx0, dx0, fmaf(dy0, dy0, dz0 * dz0));
                float d1 = fmaf(dx1, dx1, fmaf(dy1, dy1, dz1 * dz1));
                best = fminf(best, fminf(d0, d1));  // -> v_min3
            }
            if (j < e) {
                float4 c0 = C[j];
                float dx0 = q.x - c0.x, dy0 = q.y - c0.y, dz0 = q.z - c0.z;
                best = fminf(best, fmaf(dx0, dx0, fmaf(dy0, dy0, dz0 * dz0)));
            }
            b += half ? 1 : -1;
        }
        best = fminf(best, __shfl_xor(best, 32, 64));
    }
    if (half == 0) minout[qid] = best;
}

// Mean of minout[n+m].
__global__ __launch_bounds__(1024) void cd_reduce(
        const float4* __restrict__ mo, float* __restrict__ out, int total) {
    float s = 0.0f;
    for (int i = threadIdx.x; i < total / 4; i += 1024) {
        float4 v = mo[i];
        s += v.x + v.y + v.z + v.w;
    }
    for (int off = 32; off >= 1; off >>= 1) s += __shfl_down(s, off, 64);
    __shared__ float wsum[16];
    int wave = threadIdx.x >> 6;
    int lane = threadIdx.x & 63;
    if (lane == 0) wsum[wave] = s;
    __syncthreads();
    if (threadIdx.x == 0) {
        float t = 0.0f;
        for (int w = 0; w < 16; ++w) t += wsum[w];
        out[0] = t / (float)total;
    }
}

extern "C" void kernel_launch(void* const* d_in, const int* in_sizes, int n_in,
                              void* d_out, int out_size, void* d_ws, size_t ws_size,
                              hipStream_t stream) {
    const float* x = (const float*)d_in[0];
    const float* y = (const float*)d_in[1];
    const int N = in_sizes[0] / 3;  // 16384
    const int M = in_sizes[1] / 3;  // 16384

    float4* sx = (float4*)d_ws;                  // N float4 (bucket-sorted x-set)
    float4* sy = sx + N;                         // M float4
    float* minout = (float*)(sy + M);            // N+M floats
    int* hist = (int*)(minout + N + M);          // 2*NB
    int* cursor = hist + 2 * NB;                 // 2*NB
    int* starts = cursor + 2 * NB;               // 2*(NB+1)
    float* out = (float*)d_out;

    hipMemsetAsync(hist, 0, 2 * NB * sizeof(int), stream);
    cd_hist<<<(N + M + 255) / 256, 256, 0, stream>>>(x, y, hist, N, M);
    cd_scan<<<2, 1024, 0, stream>>>(hist, starts, cursor);
    cd_scatter<<<(N + M + 255) / 256, 256, 0, stream>>>(x, y, cursor, sx, sy, N, M);
    cd_search<<<(N + M) / 64, 128, 0, stream>>>(sx, sy, starts, starts + (NB + 1),
                                                minout, N, M);
    cd_reduce<<<1, 1024, 0, stream>>>((const float4*)minout, out, N + M);
}

// Round 11
// 79.534 us; speedup vs baseline: 6.8298x; 6.8298x over previous
//
#include <hip/hip_runtime.h>

// Chamfer distance, N=M=16384, D=3, f32 — EXACT sorted-window search.
// R10: R9's pruning was right (16x fewer candidate bytes) but serial-per-
// thread scanning was latency-bound (556us, 2.4% occupancy). Recast pruning
// into the R2 brute-force shape (wave-parallel LDS tiles, 107% VALUBusy):
//  1. counting-sort both sets by x (hist/scan/scatter, proven in R9)
//  2. phase 1: per owner, upper bound r from its 256 rank-neighbors
//     (rank-aligned window, valid for ANY subset); index window [lo,hi)
//     via bucket table (edge-widening => superset => exact)
//  3. phase 2: per 512-owner group, block-uniform union window sliced 16
//     ways; R2 inner loop (broadcast tile in LDS, 3 FMA + 0.5 max3/pair)
//     over ~60M pairs instead of 536M. True NN provably inside window
//     (r >= d_NN => |dx| <= r). atomicMin(uint bits) combine, d >= 0.

#define NPTS 16384
#define NB   2048
#define ORG  (-8.0f)
#define W    0.0078125f      // 1/128
#define IW   128.0f
#define GRP  512             // owners per phase-2 group
#define S2   16              // slices per group
#define P1W  256             // phase-1 rank window

__device__ __forceinline__ int bucket_of(float v) {
    int b = (int)((v - ORG) * IW);
    return min(max(b, 0), NB - 1);
}

// Histogram of x-coordinates per set. hist zeroed by memset before.
__global__ __launch_bounds__(256) void cd_hist(
        const float* __restrict__ x, const float* __restrict__ y,
        int* __restrict__ hist, int n, int m) {
    int i = blockIdx.x * 256 + threadIdx.x;
    if (i >= n + m) return;
    int set = (i < n) ? 0 : 1;
    int k = (i < n) ? i : i - n;
    const float* src = set ? y : x;
    atomicAdd(&hist[set * NB + bucket_of(src[3 * k])], 1);
}

// Exclusive scan of one set's histogram (blockIdx.x = set). Writes
// starts[set][0..NB] and cursor[set][0..NB-1].
__global__ __launch_bounds__(1024) void cd_scan(
        const int* __restrict__ hist, int* __restrict__ starts,
        int* __restrict__ cursor) {
    __shared__ int sb[2][NB];
    const int* h = hist + blockIdx.x * NB;
    int t = threadIdx.x;
    sb[0][t] = h[t];
    sb[0][t + 1024] = h[t + 1024];
    __syncthreads();
    int src = 0;
    for (int d = 1; d < NB; d <<= 1) {
        int dst = src ^ 1;
#pragma unroll
        for (int k = 0; k < 2; ++k) {
            int i = t + k * 1024;
            int v = sb[src][i];
            if (i >= d) v += sb[src][i - d];
            sb[dst][i] = v;
        }
        __syncthreads();
        src = dst;
    }
    int* st = starts + blockIdx.x * (NB + 1);
    int* cu = cursor + blockIdx.x * NB;
#pragma unroll
    for (int k = 0; k < 2; ++k) {
        int i = t + k * 1024;
        int e = (i == 0) ? 0 : sb[src][i - 1];
        st[i] = e;
        cu[i] = e;
    }
    if (t == 0) st[NB] = sb[src][NB - 1];
}

// Scatter into bucket-sorted float4 (x,y,z, 0.5|v|^2). Within-bucket order
// nondeterministic — final result provably independent of it.
__global__ __launch_bounds__(256) void cd_scatter(
        const float* __restrict__ x, const float* __restrict__ y,
        int* __restrict__ cursor, float4* __restrict__ sx,
        float4* __restrict__ sy, int n, int m) {
    int i = blockIdx.x * 256 + threadIdx.x;
    if (i >= n + m) return;
    int set = (i < n) ? 0 : 1;
    int k = (i < n) ? i : i - n;
    const float* src = set ? y : x;
    float a = src[3 * k], b = src[3 * k + 1], c = src[3 * k + 2];
    float h = 0.5f * (a * a + b * b + c * c);
    int slot = atomicAdd(&cursor[set * NB + bucket_of(a)], 1);
    float4* dst = set ? sy : sx;
    dst[slot] = make_float4(a, b, c, h);
}

// Phase 1: 4 lanes per owner scan its 256 rank-neighbors in the candidate
// set -> upper bound r; window [lo,hi) from bucket table (edge-widened =>
// superset => exact). Also initializes minout with the phase-1 best.
__global__ __launch_bounds__(256) void cd_phase1(
        const float4* __restrict__ sx, const float4* __restrict__ sy,
        const int* __restrict__ starts, int* __restrict__ loA,
        int* __restrict__ hiA, unsigned* __restrict__ minout, int n, int m) {
    int gid = blockIdx.x * 256 + threadIdx.x;
    int owner = gid >> 2, part = gid & 3;
    if (owner >= n + m) return;
    int dir = (owner < n) ? 0 : 1;
    int idx = dir ? (owner - n) : owner;
    const float4* Own = dir ? sy : sx;
    const float4* C = dir ? sx : sy;
    const int* cst = starts + (dir ? 0 : (NB + 1));  // candidate-set starts
    int NC = dir ? n : m;
    float4 p = Own[idx];
    int j0 = min(max(idx - P1W / 2, 0), NC - P1W);
    float b0 = INFINITY, b1 = INFINITY;
#pragma unroll 8
    for (int k = 0; k < P1W / 4; k += 2) {
        float4 c0 = C[j0 + part + 4 * k];
        float4 c1 = C[j0 + part + 4 * k + 4];
        float dx0 = p.x - c0.x, dy0 = p.y - c0.y, dz0 = p.z - c0.z;
        float dx1 = p.x - c1.x, dy1 = p.y - c1.y, dz1 = p.z - c1.z;
        b0 = fminf(b0, fmaf(dx0, dx0, fmaf(dy0, dy0, dz0 * dz0)));
        b1 = fminf(b1, fmaf(dx1, dx1, fmaf(dy1, dy1, dz1 * dz1)));
    }
    float best = fminf(b0, b1);
    best = fminf(best, __shfl_xor(best, 1, 64));
    best = fminf(best, __shfl_xor(best, 2, 64));
    if (part == 0) {
        float r = sqrtf(best);
        loA[owner] = cst[bucket_of(p.x - r)];
        hiA[owner] = cst[bucket_of(p.x + r) + 1];
        minout[owner] = __float_as_uint(best);
    }
}

// Phase 2: blockIdx = (group, slice, dir). 256 thr, 2 owners/thread (512
// contiguous sorted owners). Block-uniform window = union of owner windows,
// sliced S2 ways. Inner loop = R2 pattern: 256-candidate LDS tile, broadcast
// reads, per 2 cands per owner 6 FMA + 1 v_max3. atomicMin combine.
__global__ __launch_bounds__(256) void cd_phase2(
        const float4* __restrict__ sx, const float4* __restrict__ sy,
        const int* __restrict__ loA, const int* __restrict__ hiA,
        unsigned* __restrict__ minout, int n) {
    const int g = blockIdx.x, s = blockIdx.y, dir = blockIdx.z;
    const int tid = threadIdx.x;
    const float4* Own = dir ? sy : sx;
    const float4* C = dir ? sx : sy;
    const int* lo = loA + dir * n;
    const int* hi = hiA + dir * n;
    unsigned* out = minout + dir * n;
    const int obase = g * GRP;

    int l = min(lo[obase + tid], lo[obase + 256 + tid]);
    int h = max(hi[obase + tid], hi[obase + 256 + tid]);
    for (int off = 32; off; off >>= 1) {
        l = min(l, __shfl_xor(l, off, 64));
        h = max(h, __shfl_xor(h, off, 64));
    }
    __shared__ int wls[4], whs[4];
    int wave = tid >> 6, lane = tid & 63;
    if (lane == 0) { wls[wave] = l; whs[wave] = h; }
    __syncthreads();
    const int wl = min(min(wls[0], wls[1]), min(wls[2], wls[3]));
    const int wh = max(max(whs[0], whs[1]), max(whs[2], whs[3]));
    const int len = (wh - wl + S2 - 1) / S2;
    const int cb = wl + s * len;
    const int ce = min(cb + len, wh);

    const float4 p0 = Own[obase + tid];
    const float4 p1 = Own[obase + 256 + tid];
    float m0 = -INFINITY, m1 = -INFINITY;
    __shared__ __align__(16) float4 qs[256];

    for (int t0 = cb; t0 < ce; t0 += 256) {
        int j = t0 + tid;
        float4 c = make_float4(0.f, 0.f, 0.f, -1e30f);  // pad: never the max
        if (j < ce) { float4 cc = C[j]; c = make_float4(cc.x, cc.y, cc.z, -cc.w); }
        __syncthreads();
        qs[tid] = c;
        __syncthreads();
        int cnt = min(ce - t0, 256);
        if (cnt == 256) {
#pragma unroll 8
            for (int jj = 0; jj < 256; jj += 2) {
                float4 qA = qs[jj], qB = qs[jj + 1];
                float a0 = fmaf(p0.x, qA.x, fmaf(p0.y, qA.y, fmaf(p0.z, qA.z, qA.w)));
                float a1 = fmaf(p0.x, qB.x, fmaf(p0.y, qB.y, fmaf(p0.z, qB.z, qB.w)));
                m0 = fmaxf(m0, fmaxf(a0, a1));  // -> v_max3
                float a2 = fmaf(p1.x, qA.x, fmaf(p1.y, qA.y, fmaf(p1.z, qA.z, qA.w)));
                float a3 = fmaf(p1.x, qB.x, fmaf(p1.y, qB.y, fmaf(p1.z, qB.z, qB.w)));
                m1 = fmaxf(m1, fmaxf(a2, a3));
            }
        } else {
            for (int jj = 0; jj < cnt; ++jj) {
                float4 qA = qs[jj];
                m0 = fmaxf(m0, fmaf(p0.x, qA.x, fmaf(p0.y, qA.y, fmaf(p0.z, qA.z, qA.w))));
                m1 = fmaxf(m1, fmaf(p1.x, qA.x, fmaf(p1.y, qA.y, fmaf(p1.z, qA.z, qA.w))));
            }
        }
        __syncthreads();
    }

    float d0 = fmaxf(0.0f, 2.0f * (p0.w - m0));
    float d1 = fmaxf(0.0f, 2.0f * (p1.w - m1));
    atomicMin(&out[obase + tid], __float_as_uint(d0));
    atomicMin(&out[obase + 256 + tid], __float_as_uint(d1));
}

// Mean of minout[n+m] (uint bits of non-negative floats).
__global__ __launch_bounds__(1024) void cd_reduce(
        const uint4* __restrict__ mo, float* __restrict__ out, int total) {
    float s = 0.0f;
    for (int i = threadIdx.x; i < total / 4; i += 1024) {
        uint4 v = mo[i];
        s += __uint_as_float(v.x) + __uint_as_float(v.y) +
             __uint_as_float(v.z) + __uint_as_float(v.w);
    }
    for (int off = 32; off >= 1; off >>= 1) s += __shfl_down(s, off, 64);
    __shared__ float wsum[16];
    int wave = threadIdx.x >> 6;
    int lane = threadIdx.x & 63;
    if (lane == 0) wsum[wave] = s;
    __syncthreads();
    if (threadIdx.x == 0) {
        float t = 0.0f;
        for (int w = 0; w < 16; ++w) t += wsum[w];
        out[0] = t / (float)total;
    }
}

extern "C" void kernel_launch(void* const* d_in, const int* in_sizes, int n_in,
                              void* d_out, int out_size, void* d_ws, size_t ws_size,
                              hipStream_t stream) {
    const float* x = (const float*)d_in[0];
    const float* y = (const float*)d_in[1];
    const int N = in_sizes[0] / 3;  // 16384
    const int M = in_sizes[1] / 3;  // 16384

    float4* sx = (float4*)d_ws;                  // N float4 (sorted x-set)
    float4* sy = sx + N;                         // M float4 (sorted y-set)
    unsigned* minout = (unsigned*)(sy + M);      // N+M uint
    int* hist = (int*)(minout + N + M);          // 2*NB
    int* cursor = hist + 2 * NB;                 // 2*NB
    int* starts = cursor + 2 * NB;               // 2*(NB+1)
    int* loA = starts + 2 * (NB + 1);            // N+M
    int* hiA = loA + N + M;                      // N+M
    float* out = (float*)d_out;

    hipMemsetAsync(hist, 0, 2 * NB * sizeof(int), stream);
    cd_hist<<<(N + M + 255) / 256, 256, 0, stream>>>(x, y, hist, N, M);
    cd_scan<<<2, 1024, 0, stream>>>(hist, starts, cursor);
    cd_scatter<<<(N + M + 255) / 256, 256, 0, stream>>>(x, y, cursor, sx, sy, N, M);
    cd_phase1<<<((N + M) * 4 + 255) / 256, 256, 0, stream>>>(sx, sy, starts, loA,
                                                             hiA, minout, N, M);
    cd_phase2<<<dim3(NPTS / GRP, S2, 2), 256, 0, stream>>>(sx, sy, loA, hiA,
                                                           minout, N);
    cd_reduce<<<1, 1024, 0, stream>>>((const uint4*)minout, out, N + M);
}